// Round 12
// baseline (79.379 us; speedup 1.0000x reference)
//
#include <hip/hip_runtime.h>
#include <hip/hip_bf16.h>

// loss = mean((output-target)^2) + ALPHA * sum(masked cosine Gram of
// V[128][196608]), V[f][d] = conv_w[o][i][f][k], d=(site,k), site=(o,i).
//
// Round 12: r10 mixed-role structure with occupancy unlocked. Gram chunks
// shrunk to 16 sites via zero-padded K=64 (slots kk=k*16+s, k=3 zeroed once
// in prologue; exact no-ops). Tile = 128x36 dwords = 18.4KB (TS=36 keeps
// b128 reads 16B-aligned, uniform bank groups). launch_bounds(256,5) caps
// combined V+A regs ~102 (acc=64 AGPR + ~38 VGPR) -> 5 blocks/CU = 20
// waves/CU (r10: 4/16, capped by combined 128 regs). 1024 gram + 2048 mse
// blocks in one grid. Epilogue/reduce/finalize = round-9 validated.

typedef __attribute__((ext_vector_type(8))) short bf16x8;   // 8 bf16 = 4 VGPR
typedef __attribute__((ext_vector_type(4))) float f32x4;

#define ALPHA 0.0005f
#define TAU 0.2f

#define FDIM 128
#define TS 36               // tile row stride in dwords (32 data + 4 pad)
#define NGRAM 1024          // gram blocks: 64 sites = 4 chunks of 16
#define NMSE 2048           // mse blocks
#define NPAIRQ 8192         // packed u32 per partial tile
#define GRAM_ELEMS 16384
#define MSE_N4 2048000      // 8192*1000/4

// branchless RNE f32->bf16 pair pack
__device__ __forceinline__ unsigned int pack_bf2(float lo, float hi) {
    union { float f; unsigned int u; } a, b;
    a.f = lo; b.f = hi;
    unsigned int al = (a.u + 0x7fffu + ((a.u >> 16) & 1u)) >> 16;
    unsigned int bh = (b.u + 0x7fffu + ((b.u >> 16) & 1u)) & 0xffff0000u;
    return (al & 0xffffu) | bh;
}

// --------------------------------------------- mixed-role fused kernel
// blocks [0, NGRAM): Gram tile partials. [NGRAM, NGRAM+NMSE): MSE.
__global__ void __launch_bounds__(256, 5) fused_kernel(
        const float* __restrict__ o, const float* __restrict__ t,
        const float* __restrict__ conv,
        float* __restrict__ mse_part, unsigned int* __restrict__ pp) {
    __shared__ unsigned int tile[FDIM * TS];    // 18432 B
    __shared__ float red[4];
    const int tid = threadIdx.x;
    const int lane = tid & 63;
    const int wave = tid >> 6;

    if (blockIdx.x >= NGRAM) {
        // ---------------- MSE role ----------------
        const int mb = blockIdx.x - NGRAM;
        const int gid = mb * 256 + tid;
        const f32x4* o4 = reinterpret_cast<const f32x4*>(o);
        const f32x4* t4 = reinterpret_cast<const f32x4*>(t);
        float s = 0.f;
#pragma unroll 4
        for (int i = gid; i < MSE_N4; i += NMSE * 256) {
            f32x4 a = o4[i], b = t4[i];
            f32x4 d = a - b;
            s += d[0]*d[0] + d[1]*d[1] + d[2]*d[2] + d[3]*d[3];
        }
        for (int off = 32; off; off >>= 1) s += __shfl_down(s, off);
        if (lane == 0) red[wave] = s;
        __syncthreads();
        if (tid == 0) mse_part[mb] = red[0] + red[1] + red[2] + red[3];
        return;
    }

    // ---------------- Gram role ----------------
    // chunk = 16 sites. tile slot kk = k*16 + s (k=0..2 data, k=3 zeros):
    // dword col = k*8 + p holds pack(site 2p, site 2p+1); cols 24..31 = 0.
    const int p = tid >> 5;                 // site pair 0..7
    const int q = tid & 31;                 // f32x4 sub-offset 0..31
    const int colr = lane & 15;
    const int hi8 = (lane >> 4) * 8;
    const unsigned short* tileu = reinterpret_cast<const unsigned short*>(tile);

    // zero the static k=3 region once (never rewritten)
    for (int z = tid; z < FDIM * 8; z += 256)
        tile[(z >> 3) * TS + 24 + (z & 7)] = 0;

    f32x4 acc0[8], acc1[8];
#pragma unroll
    for (int cc = 0; cc < 8; ++cc) { acc0[cc] = (f32x4)0.f; acc1[cc] = (f32x4)0.f; }

    const f32x4* src4 = reinterpret_cast<const f32x4*>(conv);
    // block covers 64 sites = 6144 f32x4; chunk = 1536 f32x4
    const size_t cb = (size_t)blockIdx.x * 6144 + (2 * p) * 96 + q;

    for (int c = 0; c < 4; ++c) {
        __syncthreads();                    // tile free (prev chunk mfma done)
        f32x4 V0[3], V1[3];
#pragma unroll
        for (int jj = 0; jj < 3; ++jj) {
            V0[jj] = src4[cb + c * 1536 + 32 * jj];         // site 2p
            V1[jj] = src4[cb + c * 1536 + 96 + 32 * jj];    // site 2p+1
        }
#pragma unroll
        for (int jj = 0; jj < 3; ++jj)
#pragma unroll
            for (int u = 0; u < 4; ++u) {
                const int idx = (q + 32 * jj) * 4 + u;  // [0,384): f*3 + k
                const int f = idx / 3;                  // magic-mul
                const int k = idx - 3 * f;
                tile[f * TS + k * 8 + p] = pack_bf2(V0[jj][u], V1[jj][u]);
            }
        __syncthreads();                    // tile ready
#pragma unroll
        for (int ks = 0; ks < 2; ++ks) {
            const int koff = ks * 32 + hi8;
            bf16x8 a0 = *reinterpret_cast<const bf16x8*>(
                &tileu[(wave * 32 + colr) * (TS * 2) + koff]);
            bf16x8 a1 = *reinterpret_cast<const bf16x8*>(
                &tileu[(wave * 32 + 16 + colr) * (TS * 2) + koff]);
#pragma unroll
            for (int cc = 0; cc < 8; ++cc) {
                bf16x8 b = *reinterpret_cast<const bf16x8*>(
                    &tileu[(cc * 16 + colr) * (TS * 2) + koff]);
                acc0[cc] = __builtin_amdgcn_mfma_f32_16x16x32_bf16(a0, b, acc0[cc], 0, 0, 0);
                acc1[cc] = __builtin_amdgcn_mfma_f32_16x16x32_bf16(a1, b, acc1[cc], 0, 0, 0);
            }
        }
    }

    // epilogue: bf16-pair-packed partial tile (r9-validated layout):
    // u32[pr*128+col] = pack(G[r0], G[r0+16]), pr = wave*16 + rsub + j,
    // r0 = wave*32 + rsub + j, col = cc*16 + colr.
    unsigned int* myp = pp + (size_t)blockIdx.x * NPAIRQ;
    const int rsub = (lane >> 4) << 2;
#pragma unroll
    for (int cc = 0; cc < 8; ++cc) {
        const int col = cc * 16 + colr;
#pragma unroll
        for (int j = 0; j < 4; ++j) {
            const int pr = wave * 16 + rsub + j;
            myp[pr * FDIM + col] = pack_bf2(acc0[cc][j], acc1[cc][j]);
        }
    }
}

// ------------------------------------------------- partial reduce (bf16 pairs)
// 512 blocks x 256 thr: block owns 16 packed entries; 16 slices of 64 tiles.
__global__ void __launch_bounds__(256) reduce_kernel(
        const unsigned int* __restrict__ pp, float* __restrict__ gram) {
    __shared__ float red[16][16][2];
    const int tid = threadIdx.x;
    const int u = tid & 15;
    const int s = tid >> 4;                 // 0..15
    const int qq = blockIdx.x * 16 + u;
    float lo = 0.f, hi = 0.f;
#pragma unroll 8
    for (int b = s * 64; b < s * 64 + 64; ++b) {
        const unsigned int v = pp[(size_t)b * NPAIRQ + qq];
        lo += __uint_as_float(v << 16);
        hi += __uint_as_float(v & 0xffff0000u);
    }
    red[s][u][0] = lo; red[s][u][1] = hi;
    __syncthreads();
    if (tid < 32) {
        const int u2 = tid >> 1, h = tid & 1;
        float x = 0.f;
#pragma unroll
        for (int s2 = 0; s2 < 16; ++s2) x += red[s2][u2][h];
        gram[(blockIdx.x * 16 + u2) * 2 + h] = x;
    }
}

// ------------------------------------------------------------ finalize
// gram layout: g = (pr*128+col)*2 + h, row = (pr>>4)*32 + (pr&15) + 16h
__global__ void __launch_bounds__(256) finalize_kernel(
        const float* __restrict__ gram, const float* __restrict__ mse_part,
        float* __restrict__ out) {
    __shared__ float rn[FDIM];
    __shared__ float redS[4], redM[4];
    const int tid = threadIdx.x;
    if (tid < FDIM) {
        const int row = tid;
        const int pr = (row >> 5) * 16 + (row & 15);
        const int h = (row >> 4) & 1;
        rn[row] = rsqrtf(gram[(pr * FDIM + row) * 2 + h]);
    }
    __syncthreads();
    float s = 0.f;
    for (int i = tid; i < GRAM_ELEMS; i += 256) {
        const int h = i & 1;
        const int qq = i >> 1;
        const int col = qq & 127;
        const int pr = qq >> 7;
        const int row = (pr >> 4) * 32 + (pr & 15) + (h << 4);
        const float gv = gram[i] * rn[row] * rn[col];
        if (row != col && gv > TAU && gv <= 1.0f) s += gv;
    }
    float m = 0.f;
#pragma unroll 8
    for (int j = 0; j < 8; ++j) m += mse_part[tid * 8 + j];   // 2048 entries
    for (int off = 32; off; off >>= 1) {
        s += __shfl_down(s, off);
        m += __shfl_down(m, off);
    }
    if ((tid & 63) == 0) { redS[tid >> 6] = s; redM[tid >> 6] = m; }
    __syncthreads();
    if (tid == 0)
        out[0] = (redM[0] + redM[1] + redM[2] + redM[3]) * (1.0f / 8192000.0f) +
                 ALPHA * (redS[0] + redS[1] + redS[2] + redS[3]);
}

extern "C" void kernel_launch(void* const* d_in, const int* in_sizes, int n_in,
                              void* d_out, int out_size, void* d_ws, size_t ws_size,
                              hipStream_t stream) {
    const float* output = (const float*)d_in[0];
    const float* target = (const float*)d_in[1];
    const float* conv   = (const float*)d_in[2];
    float* out = (float*)d_out;

    float* wsf       = (float*)d_ws;
    float* mse_part  = wsf;                              // 2048 floats
    float* gram      = wsf + NMSE;                       // 16384 floats
    unsigned int* pp = (unsigned int*)(wsf + NMSE + GRAM_ELEMS); // 33.6 MB
    (void)ws_size;   // need ~33.7 MB; harness provides ~402 MB (r5 profile)

    // all buffers fully written before read -> no memsets
    fused_kernel<<<NGRAM + NMSE, 256, 0, stream>>>(output, target, conv,
                                                   mse_part, pp);
    reduce_kernel<<<NPAIRQ / 16, 256, 0, stream>>>(pp, gram);
    finalize_kernel<<<1, 256, 0, stream>>>(gram, mse_part, out);
}

// Round 14
// 64.916 us; speedup vs baseline: 1.2228x; 1.2228x over previous
//
#include <hip/hip_runtime.h>
#include <hip/hip_bf16.h>

// loss = mean((output-target)^2) + ALPHA * sum(masked cosine Gram of
// V[128][196608]), V[f][d] = conv_w[o][i][f][k], d=(site,k), site=(o,i).
//
// Round 14: r13 design with the OOB fix (block base stride 24576, not
// 49152 — r13 read 2x past conv's end and memory-faulted).
// LDS-pipe-minimal gram: staging = 2 ds_write_b128/thread/chunk
// (b128 = [x,y,z,0,x,y,z,0] for one row, one site pair); reads b128;
// row stride 20 dwords -> every bank hit exactly 8x per instr (HW min,
// 2-way aliasing only = free per m136). Loads: float3 per (row,site),
// each byte read once. 1024 blocks x 4 waves, 8 chunks of 8 sites.

typedef __attribute__((ext_vector_type(8))) short bf16x8;   // 8 bf16 = 4 VGPR
typedef __attribute__((ext_vector_type(4))) float f32x4;

#define ALPHA 0.0005f
#define TAU 0.2f

#define FDIM 128
#define TSD 20              // tile row stride in dwords (16 data + 4 pad)
#define NGRAM 1024          // gram blocks: 64 sites = 8 chunks of 8
#define BLK_FLOATS 24576    // 64 sites * 384 floats
#define NPAIRQ 8192         // packed u32 per partial tile
#define GRAM_ELEMS 16384
#define MSE_N4 2048000      // 8192*1000/4
#define MSE_NBLK 2048

// branchless RNE f32->bf16 pair pack
__device__ __forceinline__ unsigned int pack_bf2(float lo, float hi) {
    union { float f; unsigned int u; } a, b;
    a.f = lo; b.f = hi;
    unsigned int al = (a.u + 0x7fffu + ((a.u >> 16) & 1u)) >> 16;
    unsigned int bh = (b.u + 0x7fffu + ((b.u >> 16) & 1u)) & 0xffff0000u;
    return (al & 0xffffu) | bh;
}
__device__ __forceinline__ unsigned int pack_bf1(float lo) {
    union { float f; unsigned int u; } a;
    a.f = lo;
    return (a.u + 0x7fffu + ((a.u >> 16) & 1u)) >> 16;   // hi half = 0
}

// ---------------------------------------------------------------- MSE kernel
// 2048 blocks x 256 thr, 0 LDS -> 32 waves/CU (proven ~5.5 TB/s).
__global__ void __launch_bounds__(256) mse_kernel(
        const float* __restrict__ o, const float* __restrict__ t,
        float* __restrict__ mse_part) {
    __shared__ float red[4];
    const int tid = threadIdx.x;
    const float4* o4 = reinterpret_cast<const float4*>(o);
    const float4* t4 = reinterpret_cast<const float4*>(t);
    float s = 0.f;
    for (int i = blockIdx.x * 256 + tid; i < MSE_N4; i += MSE_NBLK * 256) {
        float4 a = o4[i], b = t4[i];
        float dx = a.x - b.x, dy = a.y - b.y, dz = a.z - b.z, dw = a.w - b.w;
        s += dx * dx + dy * dy + dz * dz + dw * dw;
    }
    for (int off = 32; off; off >>= 1) s += __shfl_down(s, off);
    if ((tid & 63) == 0) red[tid >> 6] = s;
    __syncthreads();
    if (tid == 0) mse_part[blockIdx.x] = red[0] + red[1] + red[2] + red[3];
}

// --------------------------------------------------------------- Gram kernel
// 1024 blocks x 256 thr (4 waves), 4 blocks/CU. Block covers 64 sites =
// 8 chunks of 8 sites. K-slots per chunk: slot pair*8 + e*4 + k, k=3 zeroed
// (exact no-op). Per chunk per thread: 4 float3 loads (row, 2 pairs x 2
// sites) -> 2 ds_write_b128; per wave: 10 ds_read_b128 + 16 MFMA.
__global__ void __launch_bounds__(256, 4) gram_kernel(
        const float* __restrict__ conv, unsigned int* __restrict__ pp) {
    __shared__ unsigned int tile[FDIM * TSD];   // 10240 B
    const int tid = threadIdx.x;
    const int lane = tid & 63;
    const int wave = tid >> 6;
    const int row = tid & 127;              // filter row this thread stages
    const int pr = tid >> 7;                // base site-pair (0 or 1)
    const int colr = lane & 15;
    const int hi8 = (lane >> 4) * 8;        // u16 offset = pair*8
    const unsigned short* tileu = reinterpret_cast<const unsigned short*>(tile);

    f32x4 acc0[8], acc1[8];
#pragma unroll
    for (int cc = 0; cc < 8; ++cc) { acc0[cc] = (f32x4)0.f; acc1[cc] = (f32x4)0.f; }

    // block base: 64 sites * 384 floats; thread offset: row*3
    const float* bp = conv + (size_t)blockIdx.x * BLK_FLOATS + row * 3;

    for (int c = 0; c < 8; ++c) {
        __syncthreads();                    // tile free (prev chunk mfma done)
        const float* cp = bp + c * 3072;    // chunk: 8 sites
#pragma unroll
        for (int z = 0; z < 2; ++z) {
            const int p2 = pr + 2 * z;      // site pair 0..3
            const float3 A = *reinterpret_cast<const float3*>(cp + (2 * p2) * 384);
            const float3 B = *reinterpret_cast<const float3*>(cp + (2 * p2) * 384 + 384);
            uint4 w;
            w.x = pack_bf2(A.x, A.y);
            w.y = pack_bf1(A.z);
            w.z = pack_bf2(B.x, B.y);
            w.w = pack_bf1(B.z);
            *reinterpret_cast<uint4*>(&tile[row * TSD + p2 * 4]) = w;
        }
        __syncthreads();                    // tile ready
        // one K=32 step: A-frags for rows wave*32+colr(+16), B-frags all rows
        bf16x8 a0 = *reinterpret_cast<const bf16x8*>(
            &tileu[(wave * 32 + colr) * (TSD * 2) + hi8]);
        bf16x8 a1 = *reinterpret_cast<const bf16x8*>(
            &tileu[(wave * 32 + 16 + colr) * (TSD * 2) + hi8]);
#pragma unroll
        for (int cc = 0; cc < 8; ++cc) {
            bf16x8 b = *reinterpret_cast<const bf16x8*>(
                &tileu[(cc * 16 + colr) * (TSD * 2) + hi8]);
            acc0[cc] = __builtin_amdgcn_mfma_f32_16x16x32_bf16(a0, b, acc0[cc], 0, 0, 0);
            acc1[cc] = __builtin_amdgcn_mfma_f32_16x16x32_bf16(a1, b, acc1[cc], 0, 0, 0);
        }
    }

    // epilogue: bf16-pair-packed partial tile (validated layout):
    // u32[pr2*128+col] = pack(G[r0], G[r0+16]), pr2 = wave*16 + rsub + j,
    // r0 = wave*32 + rsub + j, col = cc*16 + colr.
    unsigned int* myp = pp + (size_t)blockIdx.x * NPAIRQ;
    const int rsub = (lane >> 4) << 2;
#pragma unroll
    for (int cc = 0; cc < 8; ++cc) {
        const int col = cc * 16 + colr;
#pragma unroll
        for (int j = 0; j < 4; ++j) {
            const int pr2 = wave * 16 + rsub + j;
            myp[pr2 * FDIM + col] = pack_bf2(acc0[cc][j], acc1[cc][j]);
        }
    }
}

// ------------------------------------------------- partial reduce (bf16 pairs)
// 512 blocks x 256 thr: block owns 16 packed entries; 16 slices of 64 tiles.
__global__ void __launch_bounds__(256) reduce_kernel(
        const unsigned int* __restrict__ pp, float* __restrict__ gram) {
    __shared__ float red[16][16][2];
    const int tid = threadIdx.x;
    const int u = tid & 15;
    const int s = tid >> 4;                 // 0..15
    const int qq = blockIdx.x * 16 + u;
    float lo = 0.f, hi = 0.f;
#pragma unroll 8
    for (int b = s * 64; b < s * 64 + 64; ++b) {
        const unsigned int v = pp[(size_t)b * NPAIRQ + qq];
        lo += __uint_as_float(v << 16);
        hi += __uint_as_float(v & 0xffff0000u);
    }
    red[s][u][0] = lo; red[s][u][1] = hi;
    __syncthreads();
    if (tid < 32) {
        const int u2 = tid >> 1, h = tid & 1;
        float x = 0.f;
#pragma unroll
        for (int s2 = 0; s2 < 16; ++s2) x += red[s2][u2][h];
        gram[(blockIdx.x * 16 + u2) * 2 + h] = x;
    }
}

// ------------------------------------------------------------ finalize
// gram layout: g = (pr2*128+col)*2 + h, row = (pr2>>4)*32 + (pr2&15) + 16h
__global__ void __launch_bounds__(256) finalize_kernel(
        const float* __restrict__ gram, const float* __restrict__ mse_part,
        float* __restrict__ out) {
    __shared__ float rn[FDIM];
    __shared__ float redS[4], redM[4];
    const int tid = threadIdx.x;
    if (tid < FDIM) {
        const int row = tid;
        const int pr2 = (row >> 5) * 16 + (row & 15);
        const int h = (row >> 4) & 1;
        rn[row] = rsqrtf(gram[(pr2 * FDIM + row) * 2 + h]);
    }
    __syncthreads();
    float s = 0.f;
    for (int i = tid; i < GRAM_ELEMS; i += 256) {
        const int h = i & 1;
        const int qq = i >> 1;
        const int col = qq & 127;
        const int pr2 = qq >> 7;
        const int row = (pr2 >> 4) * 32 + (pr2 & 15) + (h << 4);
        const float gv = gram[i] * rn[row] * rn[col];
        if (row != col && gv > TAU && gv <= 1.0f) s += gv;
    }
    float m = 0.f;
#pragma unroll 8
    for (int j = 0; j < 8; ++j) m += mse_part[tid * 8 + j];   // 2048 entries
    for (int off = 32; off; off >>= 1) {
        s += __shfl_down(s, off);
        m += __shfl_down(m, off);
    }
    if ((tid & 63) == 0) { redS[tid >> 6] = s; redM[tid >> 6] = m; }
    __syncthreads();
    if (tid == 0)
        out[0] = (redM[0] + redM[1] + redM[2] + redM[3]) * (1.0f / 8192000.0f) +
                 ALPHA * (redS[0] + redS[1] + redS[2] + redS[3]);
}

extern "C" void kernel_launch(void* const* d_in, const int* in_sizes, int n_in,
                              void* d_out, int out_size, void* d_ws, size_t ws_size,
                              hipStream_t stream) {
    const float* output = (const float*)d_in[0];
    const float* target = (const float*)d_in[1];
    const float* conv   = (const float*)d_in[2];
    float* out = (float*)d_out;

    float* wsf       = (float*)d_ws;
    float* mse_part  = wsf;                              // 2048 floats
    float* gram      = wsf + MSE_NBLK;                   // 16384 floats
    unsigned int* pp = (unsigned int*)(wsf + MSE_NBLK + GRAM_ELEMS); // 33.6 MB
    (void)ws_size;   // need ~33.7 MB; harness provides ~402 MB (r5 profile)

    // all buffers fully written before read -> no memsets
    gram_kernel<<<NGRAM, 256, 0, stream>>>(conv, pp);
    mse_kernel<<<MSE_NBLK, 256, 0, stream>>>(output, target, mse_part);
    reduce_kernel<<<NPAIRQ / 16, 256, 0, stream>>>(pp, gram);
    finalize_kernel<<<1, 256, 0, stream>>>(gram, mse_part, out);
}

// Round 15
// 64.551 us; speedup vs baseline: 1.2297x; 1.0056x over previous
//
#include <hip/hip_runtime.h>
#include <hip/hip_bf16.h>

// loss = mean((output-target)^2) + ALPHA * sum(masked cosine Gram of
// V[128][196608]), V[f][d] = conv_w[o][i][f][k], d=(site,k), site=(o,i).
//
// Round 15: consolidation on r10 (best: 57.8us). Mixed-role grid is the
// proven winner (mse waves fill gram barrier stalls). Changes vs r10:
// 256 gram blocks x 8 chunks (halves pp round-trip to 8.4MB; gram blocks
// co-resident with mse for the whole kernel), NMSE 2048 (proven standalone
// config). Gram inner loop identical to r10. reduce = r8 validated shape;
// finalize = r14 validated.

typedef __attribute__((ext_vector_type(8))) short bf16x8;   // 8 bf16 = 4 VGPR
typedef __attribute__((ext_vector_type(4))) float f32x4;

#define ALPHA 0.0005f
#define TAU 0.2f

#define FDIM 128
#define TSTRIDE 52          // tile row stride in dwords (48 data + 4 pad)
#define GRAM_NBLK 256       // gram-role blocks: 8 chunks of 32 sites each
#define NMSE 2048           // mse-role blocks
#define CHUNK_F4 3072       // 32 sites * 96 float4
#define GRAM_ELEMS 16384
#define NPAIRQ 8192         // packed u32 per partial tile
#define MSE_N4 2048000      // 8192*1000/4

// branchless RNE f32->bf16 pair pack
__device__ __forceinline__ unsigned int pack_bf2(float lo, float hi) {
    union { float f; unsigned int u; } a, b;
    a.f = lo; b.f = hi;
    unsigned int al = (a.u + 0x7fffu + ((a.u >> 16) & 1u)) >> 16;
    unsigned int bh = (b.u + 0x7fffu + ((b.u >> 16) & 1u)) & 0xffff0000u;
    return (al & 0xffffu) | bh;
}

__device__ __forceinline__ void mfmaph(const unsigned short* __restrict__ tu,
                                       int wave, int colr, int hi8,
                                       f32x4 (&acc0)[8], f32x4 (&acc1)[8]) {
#pragma unroll
    for (int ks = 0; ks < 3; ++ks) {
        const int koff = ks * 32 + hi8;
        bf16x8 a0 = *reinterpret_cast<const bf16x8*>(
            &tu[(wave * 32 + colr) * (TSTRIDE * 2) + koff]);
        bf16x8 a1 = *reinterpret_cast<const bf16x8*>(
            &tu[(wave * 32 + 16 + colr) * (TSTRIDE * 2) + koff]);
#pragma unroll
        for (int cc = 0; cc < 8; ++cc) {
            bf16x8 b = *reinterpret_cast<const bf16x8*>(
                &tu[(cc * 16 + colr) * (TSTRIDE * 2) + koff]);
            acc0[cc] = __builtin_amdgcn_mfma_f32_16x16x32_bf16(a0, b, acc0[cc], 0, 0, 0);
            acc1[cc] = __builtin_amdgcn_mfma_f32_16x16x32_bf16(a1, b, acc1[cc], 0, 0, 0);
        }
    }
}

// --------------------------------------------- mixed-role fused kernel
// blocks [0, GRAM_NBLK): Gram tile partials. [GRAM_NBLK, +NMSE): MSE.
__global__ void __launch_bounds__(256, 4) fused_kernel(
        const float* __restrict__ o, const float* __restrict__ t,
        const float* __restrict__ conv,
        float* __restrict__ mse_part, unsigned int* __restrict__ pp) {
    __shared__ unsigned int tile[FDIM * TSTRIDE];   // 26624 B
    __shared__ float red[4];
    const int tid = threadIdx.x;
    const int lane = tid & 63;
    const int wave = tid >> 6;

    if (blockIdx.x >= GRAM_NBLK) {
        // ---------------- MSE role ----------------
        const int mb = blockIdx.x - GRAM_NBLK;
        const int gid = mb * 256 + tid;
        const f32x4* o4 = reinterpret_cast<const f32x4*>(o);
        const f32x4* t4 = reinterpret_cast<const f32x4*>(t);
        float s = 0.f;
        for (int i = gid; i < MSE_N4; i += NMSE * 256) {
            f32x4 a = o4[i], b = t4[i];
            f32x4 d = a - b;
            s += d[0]*d[0] + d[1]*d[1] + d[2]*d[2] + d[3]*d[3];
        }
        for (int off = 32; off; off >>= 1) s += __shfl_down(s, off);
        if (lane == 0) red[wave] = s;
        __syncthreads();
        if (tid == 0) mse_part[mb] = red[0] + red[1] + red[2] + red[3];
        return;
    }

    // ---------------- Gram role (r10 inner loop, 8 chunks) ----------------
    const int p = tid >> 4;                 // site pair 0..15
    const int q = tid & 15;                 // float4 sub-offset 0..15
    const int colr = lane & 15;
    const int hi8 = (lane >> 4) * 8;
    const unsigned short* tileu = reinterpret_cast<const unsigned short*>(tile);

    f32x4 acc0[8], acc1[8];
#pragma unroll
    for (int cc = 0; cc < 8; ++cc) { acc0[cc] = (f32x4)0.f; acc1[cc] = (f32x4)0.f; }

    const f32x4* src4 = reinterpret_cast<const f32x4*>(conv);
    const size_t cb = (size_t)blockIdx.x * (8 * CHUNK_F4) + (2 * p) * 96 + q;

    for (int c = 0; c < 8; ++c) {
        __syncthreads();                    // tile free (prev chunk's mfma done)
        // stage+convert: 6 x (2 f32x4 loads -> 4 packed b32 LDS writes).
#pragma unroll
        for (int it = 0; it < 6; ++it) {
            const f32x4 v0 = src4[cb + c * CHUNK_F4 + 16 * it];
            const f32x4 v1 = src4[cb + c * CHUNK_F4 + 96 + 16 * it];
            const int off4 = q + 16 * it;
#pragma unroll
            for (int u = 0; u < 4; ++u) {
                const int idx = off4 * 4 + u;       // [0,384): f*3 + k
                const int f = idx / 3;              // magic-mul
                const int k = idx - 3 * f;
                tile[f * TSTRIDE + k * 16 + p] = pack_bf2(v0[u], v1[u]);
            }
        }
        __syncthreads();                    // tile ready
        mfmaph(tileu, wave, colr, hi8, acc0, acc1);
    }

    // epilogue: bf16-pair-packed partial tile (validated layout):
    // u32[pr*128+col] = pack(G[r0], G[r0+16]), pr = wave*16 + rsub + j,
    // r0 = wave*32 + rsub + j, col = cc*16 + colr.
    unsigned int* myp = pp + (size_t)blockIdx.x * NPAIRQ;
    const int rsub = (lane >> 4) << 2;
#pragma unroll
    for (int cc = 0; cc < 8; ++cc) {
        const int col = cc * 16 + colr;
#pragma unroll
        for (int j = 0; j < 4; ++j) {
            const int pr = wave * 16 + rsub + j;
            myp[pr * FDIM + col] = pack_bf2(acc0[cc][j], acc1[cc][j]);
        }
    }
}

// ------------------------------------------------- partial reduce (bf16 pairs)
// 512 blocks x 256 thr: block owns 16 packed entries; 16 slices of 16 tiles.
// (validated in round 8 with 256 tiles)
__global__ void __launch_bounds__(256) reduce_kernel(
        const unsigned int* __restrict__ pp, float* __restrict__ gram) {
    __shared__ float red[16][16][2];
    const int tid = threadIdx.x;
    const int u = tid & 15;
    const int s = tid >> 4;                 // 0..15
    const int qq = blockIdx.x * 16 + u;
    float lo = 0.f, hi = 0.f;
#pragma unroll 8
    for (int b = s * 16; b < s * 16 + 16; ++b) {
        const unsigned int v = pp[(size_t)b * NPAIRQ + qq];
        lo += __uint_as_float(v << 16);
        hi += __uint_as_float(v & 0xffff0000u);
    }
    red[s][u][0] = lo; red[s][u][1] = hi;
    __syncthreads();
    if (tid < 32) {
        const int u2 = tid >> 1, h = tid & 1;
        float x = 0.f;
#pragma unroll
        for (int s2 = 0; s2 < 16; ++s2) x += red[s2][u2][h];
        gram[(blockIdx.x * 16 + u2) * 2 + h] = x;
    }
}

// ------------------------------------------------------------ finalize
// gram layout: g = (pr*128+col)*2 + h, row = (pr>>4)*32 + (pr&15) + 16h
// (validated in rounds 12/14 with 2048 mse entries)
__global__ void __launch_bounds__(256) finalize_kernel(
        const float* __restrict__ gram, const float* __restrict__ mse_part,
        float* __restrict__ out) {
    __shared__ float rn[FDIM];
    __shared__ float redS[4], redM[4];
    const int tid = threadIdx.x;
    if (tid < FDIM) {
        const int row = tid;
        const int pr = (row >> 5) * 16 + (row & 15);
        const int h = (row >> 4) & 1;
        rn[row] = rsqrtf(gram[(pr * FDIM + row) * 2 + h]);
    }
    __syncthreads();
    float s = 0.f;
    for (int i = tid; i < GRAM_ELEMS; i += 256) {
        const int h = i & 1;
        const int qq = i >> 1;
        const int col = qq & 127;
        const int pr = qq >> 7;
        const int row = (pr >> 4) * 32 + (pr & 15) + (h << 4);
        const float gv = gram[i] * rn[row] * rn[col];
        if (row != col && gv > TAU && gv <= 1.0f) s += gv;
    }
    float m = 0.f;
#pragma unroll 8
    for (int j = 0; j < 8; ++j) m += mse_part[tid * 8 + j];   // 2048 entries
    for (int off = 32; off; off >>= 1) {
        s += __shfl_down(s, off);
        m += __shfl_down(m, off);
    }
    if ((tid & 63) == 0) { redS[tid >> 6] = s; redM[tid >> 6] = m; }
    __syncthreads();
    if (tid == 0)
        out[0] = (redM[0] + redM[1] + redM[2] + redM[3]) * (1.0f / 8192000.0f) +
                 ALPHA * (redS[0] + redS[1] + redS[2] + redS[3]);
}

extern "C" void kernel_launch(void* const* d_in, const int* in_sizes, int n_in,
                              void* d_out, int out_size, void* d_ws, size_t ws_size,
                              hipStream_t stream) {
    const float* output = (const float*)d_in[0];
    const float* target = (const float*)d_in[1];
    const float* conv   = (const float*)d_in[2];
    float* out = (float*)d_out;

    float* wsf       = (float*)d_ws;
    float* mse_part  = wsf;                              // 2048 floats
    float* gram      = wsf + NMSE;                       // 16384 floats
    unsigned int* pp = (unsigned int*)(wsf + NMSE + GRAM_ELEMS); // 8.4 MB
    (void)ws_size;   // need ~8.5 MB; harness provides ~402 MB (r5 profile)

    // all buffers fully written before read -> no memsets
    fused_kernel<<<GRAM_NBLK + NMSE, 256, 0, stream>>>(output, target, conv,
                                                       mse_part, pp);
    reduce_kernel<<<NPAIRQ / 16, 256, 0, stream>>>(pp, gram);
    finalize_kernel<<<1, 256, 0, stream>>>(gram, mse_part, out);
}